// Round 8
// baseline (223.072 us; speedup 1.0000x reference)
//
#include <hip/hip_runtime.h>
#include <hip/hip_bf16.h>
#include <math.h>

// GAT forward. N=4096, Fin=512, H=8, D=64, C=64.
// Round 8:
//  - attn_v4: 128-wide j-tiles, lane owns a j-PAIR (2l, 2l+1). Masks repacked
//    into even/odd u64 words (bit l = col 2l / 2l+1) so masking stays ONE
//    v_cndmask per element; p-pair packed via v_cvt_pk_bf16_f32 + ds_write_b32.
//    ROWS=32 blocks (16KB LDS dbuf) -> 2x grid for barrier-stall hiding.
//  - pack_mask emits the even/odd format via shfl+ballot (coalesced reads).

#define N_NODES 4096
#define FIN 512
#define NHEAD 8
#define DHEAD 64
#define NCLS 64

typedef unsigned short u16;
typedef unsigned long long u64;
typedef __attribute__((ext_vector_type(8))) short bf16x8;
typedef __attribute__((ext_vector_type(4))) float f32x4;

__device__ __forceinline__ float lrelu02(float x) { return x > 0.f ? x : 0.2f * x; }
__device__ __forceinline__ u16 bf16u(float x) {
    __hip_bfloat16 h = __float2bfloat16(x);
    return __builtin_bit_cast(unsigned short, h);
}
__device__ __forceinline__ f32x4 mfma16(bf16x8 a, bf16x8 b, f32x4 c) {
    return __builtin_amdgcn_mfma_f32_16x16x32_bf16(a, b, c, 0, 0, 0);
}
__device__ __forceinline__ unsigned fkey(float f) {
    unsigned u = __builtin_bit_cast(unsigned, f);
    return (u & 0x80000000u) ? ~u : (u | 0x80000000u);
}
__device__ __forceinline__ float funkey(unsigned k) {
    unsigned u = (k & 0x80000000u) ? (k ^ 0x80000000u) : ~k;
    return __builtin_bit_cast(float, u);
}

// ---------------- adjacency -> even/odd bit words ----------------
// mb2[row][t128][2]: word0 bit l = adj(row, t128*128 + 2l) ; word1 bit l = 2l+1.
__global__ void pack_mask(const int* __restrict__ adj, u64* __restrict__ mb2,
                          unsigned* __restrict__ gmk) {
    if (blockIdx.x == 0 && threadIdx.x < 16) gmk[threadIdx.x] = 0u;
    int nwaves = (gridDim.x * blockDim.x) >> 6;
    int wid = (blockIdx.x * blockDim.x + threadIdx.x) >> 6;
    int lane = threadIdx.x & 63;
    const int sl = (2 * lane) & 63;       // src lane for even bit
    const int slo = (2 * lane + 1) & 63;  // src lane for odd bit
    for (int w = wid; w < N_NODES * 32; w += nwaves) {
        int i = w >> 5, t128 = w & 31;
        const int* base = adj + (size_t)i * N_NODES + t128 * 128;
        int v0 = base[lane];
        int v1 = base[64 + lane];
        int e0 = __shfl(v0, sl), e1 = __shfl(v1, sl);
        int o0 = __shfl(v0, slo), o1 = __shfl(v1, slo);
        u64 be = __ballot((lane < 32 ? e0 : e1) > 0);
        u64 bo = __ballot((lane < 32 ? o0 : o1) > 0);
        if (lane == 0) {
            mb2[(size_t)w * 2] = be;
            mb2[(size_t)w * 2 + 1] = bo;
        }
    }
}

// ---------------- fp32 -> bf16 flat convert ----------------
__global__ void cvt4(const float* __restrict__ s, u16* __restrict__ d, int n4) {
    int i = blockIdx.x * blockDim.x + threadIdx.x;
    if (i < n4) {
        float4 v = ((const float4*)s)[i];
        ushort4 o = {bf16u(v.x), bf16u(v.y), bf16u(v.z), bf16u(v.w)};
        ((ushort4*)d)[i] = o;
    }
}

// ---------------- fp32 [rows][ldsrc] (64-col slice) -> bf16 transposed [64][ldd] ----
__global__ __launch_bounds__(256) void to_bf16_T(
    const float* __restrict__ src, int ldsrc, size_t cstep,
    u16* __restrict__ dst, size_t dstep, int ldd) {
    __shared__ alignas(16) u16 T[64][72];
    const int j0 = blockIdx.x * 64;
    const size_t c0 = (size_t)blockIdx.y * cstep;
    u16* d = dst + (size_t)blockIdx.y * dstep;
    const int t = threadIdx.x;
    const int row = t & 63, g = t >> 6;
    #pragma unroll
    for (int k = 0; k < 16; k += 4) {
        float4 v = *(const float4*)(src + (size_t)(j0 + row) * ldsrc + c0 + g * 16 + k);
        T[g * 16 + k + 0][row] = bf16u(v.x);
        T[g * 16 + k + 1][row] = bf16u(v.y);
        T[g * 16 + k + 2][row] = bf16u(v.z);
        T[g * 16 + k + 3][row] = bf16u(v.w);
    }
    __syncthreads();
    const int dd = t >> 2, jc = (t & 3) * 16;
    *(uint4*)(d + (size_t)dd * ldd + j0 + jc) = *(const uint4*)&T[dd][jc];
    *(uint4*)(d + (size_t)dd * ldd + j0 + jc + 8) = *(const uint4*)&T[dd][jc + 8];
}

// ---------------- fused MFMA GEMM (x@W / h@Wo + f1/f2 + gmax + bf16-T out) ----
__global__ __launch_bounds__(256) void gemm_fused(
    const u16* __restrict__ A, int lda, const u16* __restrict__ Bt, int ldb,
    const float* __restrict__ a1a, const float* __restrict__ a2a,
    u16* __restrict__ WhBT, float* __restrict__ f1o, float* __restrict__ f2o,
    unsigned* __restrict__ gmk, int K) {
    __shared__ alignas(16) u16 T[64][72];
    const int t = threadIdx.x, lane = t & 63, wv = t >> 6;
    const int c16 = lane & 15, kg = lane >> 4;
    const int h = blockIdx.x;
    const int bm = blockIdx.y * 64;
    const u16* Ap = A + (size_t)(bm + wv * 16 + c16) * lda + kg * 8;
    const u16* Bp = Bt + (size_t)(h * 64 + c16) * ldb + kg * 8;
    f32x4 acc[4] = {};
    #pragma unroll 4
    for (int k0 = 0; k0 < K; k0 += 32) {
        bf16x8 a = *(const bf16x8*)(Ap + k0);
        #pragma unroll
        for (int ct = 0; ct < 4; ++ct) {
            bf16x8 b = *(const bf16x8*)(Bp + (size_t)ct * 16 * ldb + k0);
            acc[ct] = mfma16(a, b, acc[ct]);
        }
    }
    float a1v[4], a2v[4];
    #pragma unroll
    for (int ct = 0; ct < 4; ++ct) {
        a1v[ct] = a1a[h * 64 + ct * 16 + c16];
        a2v[ct] = a2a[h * 64 + ct * 16 + c16];
    }
    float mx = -1e30f;
    #pragma unroll
    for (int r = 0; r < 4; ++r) {
        float s1 = 0.f, s2 = 0.f;
        int rl = wv * 16 + kg * 4 + r;
        #pragma unroll
        for (int ct = 0; ct < 4; ++ct) {
            float v = acc[ct][r];
            s1 = fmaf(v, a1v[ct], s1);
            s2 = fmaf(v, a2v[ct], s2);
            T[ct * 16 + c16][rl] = bf16u(v);
        }
        #pragma unroll
        for (int off = 1; off < 16; off <<= 1) {
            s1 += __shfl_xor(s1, off, 64);
            s2 += __shfl_xor(s2, off, 64);
        }
        if (c16 == 0) {
            f1o[(size_t)h * N_NODES + bm + rl] = s1;
            f2o[(size_t)h * N_NODES + bm + rl] = s2;
        }
        mx = fmaxf(mx, s2);
    }
    mx = fmaxf(mx, __shfl_xor(mx, 16, 64));
    mx = fmaxf(mx, __shfl_xor(mx, 32, 64));
    if (lane == 0) atomicMax(&gmk[h], fkey(mx));
    __syncthreads();
    const int dd = t >> 2, jc = (t & 3) * 16;
    u16* dst = WhBT + (size_t)(h * 64 + dd) * N_NODES + bm;
    *(uint4*)(dst + jc) = *(const uint4*)&T[dd][jc];
    *(uint4*)(dst + jc + 8) = *(const uint4*)&T[dd][jc + 8];
}

// ---------------- per-row / per-col softmax coefficients ----------------
__global__ void coefk(const float* __restrict__ f1, const float* __restrict__ f2,
                      const unsigned* __restrict__ gmk, float4* __restrict__ rowc,
                      float2* __restrict__ uv) {
    int h = blockIdx.y;
    int i = blockIdx.x * 256 + threadIdx.x;
    float g = funkey(gmk[h]);
    float a = f1[(size_t)h * N_NODES + i];
    float s = a + g;
    float M = lrelu02(s);
    rowc[(size_t)h * N_NODES + i] = make_float4(__expf(s - M), __expf(0.2f * s - M), 0.f, 0.f);
    float b = f2[(size_t)h * N_NODES + i] - g;
    uv[(size_t)h * N_NODES + i] = make_float2(__expf(b), __expf(0.2f * b));
}

// ---------------- attention v4: 128-wide tiles, pair-packed p-phase ----------
// OUTF 1: fp32 row-major partial [js][4096][512] (NH=8)
// OUTF 3: fp32 transposed partial [js][64][4096]  (NH=1)
template <int NH, int ROWS, int JSPLIT, int OUTF>
__global__ __launch_bounds__(256) void attn_v4(
    const u16* __restrict__ WhB, const float2* __restrict__ uv,
    const float4* __restrict__ rowc, const u64* __restrict__ mb2,
    float* __restrict__ outp, float* __restrict__ denP) {
    constexpr int NQ = ROWS / 4;
    constexpr int NMT = ROWS / 16;
    constexpr int NT = 32 / JSPLIT;  // 128-wide tiles per block
    __shared__ alignas(16) u16 pS[2][ROWS][128];
    __shared__ float Tof[(OUTF == 3) ? 64 * (ROWS + 1) : 1];
    const int b = blockIdx.x;
    int h, ib, js;
    if (NH == 8) { h = b & 7; int r = b >> 3; js = r % JSPLIT; ib = r / JSPLIT; }
    else { h = 0; js = b % JSPLIT; ib = b / JSPLIT; }
    const int i0 = ib * ROWS;
    const int t0 = js * NT;
    const int t = threadIdx.x, lane = t & 63, wv = t >> 6;
    const int wv_u = __builtin_amdgcn_readfirstlane(wv);

    const float2* __restrict__ uvp = uv + (size_t)h * N_NODES;
    const float4* __restrict__ rcp = rowc + (size_t)h * N_NODES;
    const u64* __restrict__ mbp = mb2 + (size_t)(i0 + wv_u) * 64 + t0 * 2;

    float Aq[NQ], Bq[NQ], den[NQ];
    #pragma unroll
    for (int q = 0; q < NQ; ++q) {
        float4 rc = rcp[i0 + q * 4 + wv];
        Aq[q] = rc.x; Bq[q] = rc.y; den[q] = 0.f;
    }
    // u16-index write cols for the j-pair (row&7 = wv for even q, wv+4 for odd q)
    const int wcE = (2 * lane) ^ (wv << 3);
    const int wcO = (2 * lane) ^ ((wv + 4) << 3);
    const int kg = lane >> 4, c16 = lane & 15;
    const int ocol = wv * 16 + c16;
    const u16* bbase = WhB + ((size_t)h * 64 + ocol) * N_NODES + t0 * 128 + kg * 8;
    const int sw8 = (c16 & 7) << 3;
    f32x4 acc[NMT] = {};

    // prologue: tile-0 operands
    bf16x8 bfr[4];
    #pragma unroll
    for (int kc = 0; kc < 4; ++kc) bfr[kc] = *(const bf16x8*)(bbase + kc * 32);
    float4 uvv = *(const float4*)&uvp[(size_t)t0 * 128 + 2 * lane];
    u64 me[NQ], mo[NQ];
    #pragma unroll
    for (int q = 0; q < NQ; ++q) { me[q] = mbp[q * 256]; mo[q] = mbp[q * 256 + 1]; }

    for (int it = 0; it < NT; ++it) {
        const int buf = it & 1;
        const int nit = (it + 1 < NT) ? it + 1 : it;
        // prefetch next-tile B / uv (consumed next iteration)
        bf16x8 nb[4];
        #pragma unroll
        for (int kc = 0; kc < 4; ++kc)
            nb[kc] = *(const bf16x8*)(bbase + (size_t)nit * 128 + kc * 32);
        float4 nuv = *(const float4*)&uvp[((size_t)t0 + nit) * 128 + 2 * lane];
        // p-phase: 2 entries per thread per q
        #pragma unroll
        for (int q = 0; q < NQ; ++q) {
            unsigned le = __builtin_amdgcn_readfirstlane((unsigned)me[q]);
            unsigned he = __builtin_amdgcn_readfirstlane((unsigned)(me[q] >> 32));
            unsigned lo2 = __builtin_amdgcn_readfirstlane((unsigned)mo[q]);
            unsigned ho2 = __builtin_amdgcn_readfirstlane((unsigned)(mo[q] >> 32));
            u64 wse = ((u64)he << 32) | le;
            u64 wso = ((u64)ho2 << 32) | lo2;
            float te = fmaxf(Aq[q] * uvv.x, Bq[q] * uvv.y);
            float to = fmaxf(Aq[q] * uvv.z, Bq[q] * uvv.w);
            float pe, po;
            asm("v_cndmask_b32 %0, 0, %1, %2" : "=v"(pe) : "v"(te), "s"(wse));
            asm("v_cndmask_b32 %0, 0, %1, %2" : "=v"(po) : "v"(to), "s"(wso));
            den[q] += pe + po;
            unsigned pk;
            asm("v_cvt_pk_bf16_f32 %0, %1, %2" : "=v"(pk) : "v"(pe), "v"(po));
            *(unsigned*)&pS[buf][q * 4 + wv][(q & 1) ? wcO : wcE] = pk;
        }
        // current masks dead: issue next-tile mask loads (drain under MFMA)
        #pragma unroll
        for (int q = 0; q < NQ; ++q) {
            me[q] = mbp[q * 256 + nit * 2];
            mo[q] = mbp[q * 256 + nit * 2 + 1];
        }
        __syncthreads();
        __builtin_amdgcn_s_setprio(1);
        #pragma unroll
        for (int mt = 0; mt < NMT; ++mt) {
            const u16* ap = &pS[buf][mt * 16 + c16][0];
            #pragma unroll
            for (int kc = 0; kc < 4; ++kc) {
                bf16x8 a = *(const bf16x8*)&ap[(kc * 32 + kg * 8) ^ sw8];
                acc[mt] = mfma16(a, bfr[kc], acc[mt]);
            }
        }
        __builtin_amdgcn_s_setprio(0);
        #pragma unroll
        for (int kc = 0; kc < 4; ++kc) bfr[kc] = nb[kc];
        uvv = nuv;
    }

    #pragma unroll
    for (int q = 0; q < NQ; ++q) {
        float s = den[q];
        #pragma unroll
        for (int off = 32; off; off >>= 1) s += __shfl_xor(s, off, 64);
        den[q] = s;
    }

    if constexpr (OUTF == 1) {
        if (lane == 0) {
            #pragma unroll
            for (int q = 0; q < NQ; ++q)
                denP[(size_t)js * (8 * N_NODES) + (size_t)h * N_NODES + i0 + q * 4 + wv] = den[q];
        }
        float* dst = outp + (size_t)js * N_NODES * 512;
        #pragma unroll
        for (int mt = 0; mt < NMT; ++mt)
            #pragma unroll
            for (int r = 0; r < 4; ++r)
                dst[(size_t)(i0 + mt * 16 + kg * 4 + r) * 512 + h * 64 + ocol] = acc[mt][r];
    } else {
        if (lane == 0) {
            #pragma unroll
            for (int q = 0; q < NQ; ++q)
                denP[(size_t)js * N_NODES + i0 + q * 4 + wv] = den[q];
        }
        #pragma unroll
        for (int mt = 0; mt < NMT; ++mt)
            #pragma unroll
            for (int r = 0; r < 4; ++r)
                Tof[ocol * (ROWS + 1) + mt * 16 + kg * 4 + r] = acc[mt][r];
        __syncthreads();
        const int c = t >> 2, r0 = (t & 3) * 8;
        float* dst = outp + (size_t)js * 64 * N_NODES + (size_t)c * N_NODES + i0 + r0;
        float4 v0 = {Tof[c * (ROWS + 1) + r0 + 0], Tof[c * (ROWS + 1) + r0 + 1],
                     Tof[c * (ROWS + 1) + r0 + 2], Tof[c * (ROWS + 1) + r0 + 3]};
        float4 v1 = {Tof[c * (ROWS + 1) + r0 + 4], Tof[c * (ROWS + 1) + r0 + 5],
                     Tof[c * (ROWS + 1) + r0 + 6], Tof[c * (ROWS + 1) + r0 + 7]};
        *(float4*)(dst) = v0;
        *(float4*)(dst + 4) = v1;
    }
}

// ---------------- combine attn8 partials -> bf16 hB ----------------
__global__ __launch_bounds__(256) void combine8(
    const float* __restrict__ part, const float* __restrict__ denp,
    u16* __restrict__ hB) {
    const int t4 = (blockIdx.x * 256 + threadIdx.x) * 4;
    const int i = t4 >> 9, c = t4 & 511, h = c >> 6;
    float4 p0 = *(const float4*)(part + t4);
    float4 p1 = *(const float4*)(part + (size_t)N_NODES * 512 + t4);
    float d = denp[h * N_NODES + i] + denp[8 * N_NODES + h * N_NODES + i];
    float inv = d > 0.f ? 1.f / d : 0.f;
    float v[4] = {(p0.x + p1.x) * inv, (p0.y + p1.y) * inv,
                  (p0.z + p1.z) * inv, (p0.w + p1.w) * inv};
    ushort4 o;
    #pragma unroll
    for (int k = 0; k < 4; ++k) {
        float e = v[k] > 0.f ? v[k] : expm1f(v[k]);
        ((u16*)&o)[k] = bf16u(e);
    }
    *(ushort4*)(hB + t4) = o;
}

// ---------------- combine attn1 partials + ELU + log_softmax -> bf16 lsT ------
__global__ __launch_bounds__(256) void combine1_lsm(
    const float* __restrict__ partT, const float* __restrict__ denp,
    u16* __restrict__ lsT) {
    __shared__ float vb[N_NODES];
    __shared__ float r[256];
    const int c = blockIdx.x, t = threadIdx.x;
    float m = -1e30f;
    for (int i = t * 4; i < N_NODES; i += 1024) {
        float4 s = {0.f, 0.f, 0.f, 0.f}, d = {0.f, 0.f, 0.f, 0.f};
        #pragma unroll
        for (int js = 0; js < 8; ++js) {
            float4 pv = *(const float4*)(partT + (size_t)js * 64 * N_NODES +
                                         (size_t)c * N_NODES + i);
            float4 dv = *(const float4*)(denp + (size_t)js * N_NODES + i);
            s.x += pv.x; s.y += pv.y; s.z += pv.z; s.w += pv.w;
            d.x += dv.x; d.y += dv.y; d.z += dv.z; d.w += dv.w;
        }
        float vv[4] = {d.x > 0.f ? s.x / d.x : 0.f, d.y > 0.f ? s.y / d.y : 0.f,
                       d.z > 0.f ? s.z / d.z : 0.f, d.w > 0.f ? s.w / d.w : 0.f};
        #pragma unroll
        for (int k = 0; k < 4; ++k) {
            float e = vv[k] > 0.f ? vv[k] : expm1f(vv[k]);
            vb[i + k] = e;
            m = fmaxf(m, e);
        }
    }
    r[t] = m;
    __syncthreads();
    for (int s = 128; s; s >>= 1) {
        if (t < s) r[t] = fmaxf(r[t], r[t + s]);
        __syncthreads();
    }
    m = r[0];
    __syncthreads();
    float sum = 0.f;
    for (int i = t; i < N_NODES; i += 256) sum += __expf(vb[i] - m);
    r[t] = sum;
    __syncthreads();
    for (int s = 128; s; s >>= 1) {
        if (t < s) r[t] += r[t + s];
        __syncthreads();
    }
    float lse = m + __logf(r[0]);
    for (int i = t * 4; i < N_NODES; i += 1024) {
        ushort4 o = {bf16u(vb[i] - lse), bf16u(vb[i + 1] - lse),
                     bf16u(vb[i + 2] - lse), bf16u(vb[i + 3] - lse)};
        *(ushort4*)(lsT + (size_t)c * N_NODES + i) = o;
    }
}

// ---------------- mlp1: split-K MFMA  part[ks][64 c][512 o] ----------------
__global__ __launch_bounds__(256) void mlp1_mfma(
    const u16* __restrict__ lsT, const u16* __restrict__ W1B,
    float* __restrict__ part) {
    const int t = threadIdx.x, lane = t & 63, wv = t >> 6;
    const int c16 = lane & 15, kg = lane >> 4;
    const int ks = blockIdx.x & 15;
    const int bn = (blockIdx.x >> 4) * 64;
    const int kb = ks * 256;
    const u16* Ap = lsT + (size_t)(wv * 16 + c16) * N_NODES + kb + kg * 8;
    const u16* Bp = W1B + (size_t)(bn + c16) * N_NODES + kb + kg * 8;
    f32x4 acc[4] = {};
    #pragma unroll
    for (int k0 = 0; k0 < 256; k0 += 32) {
        bf16x8 a = *(const bf16x8*)(Ap + k0);
        #pragma unroll
        for (int ct = 0; ct < 4; ++ct) {
            bf16x8 b = *(const bf16x8*)(Bp + (size_t)ct * 16 * N_NODES + k0);
            acc[ct] = mfma16(a, b, acc[ct]);
        }
    }
    float* dst = part + (size_t)ks * 64 * 512;
    #pragma unroll
    for (int ct = 0; ct < 4; ++ct)
        #pragma unroll
        for (int r = 0; r < 4; ++r)
            dst[(size_t)(wv * 16 + kg * 4 + r) * 512 + bn + ct * 16 + c16] = acc[ct][r];
}

__global__ void mlp1_fin(const float* __restrict__ part, const float* __restrict__ b1,
                         float* __restrict__ y1) {
    int idx = blockIdx.x * 256 + threadIdx.x;
    int o = idx & 511;
    float s = 0.f;
    #pragma unroll
    for (int ks = 0; ks < 16; ++ks) s += part[(size_t)ks * 32768 + idx];
    s += b1[o];
    y1[idx] = s > 0.f ? s : 0.1f * s;
}

// ---------------- mlp2 ----------------
__global__ __launch_bounds__(256) void mlp2(
    const float* __restrict__ y1, const float* __restrict__ W2,
    const float* __restrict__ b2, float* __restrict__ out) {
    __shared__ alignas(16) float row[512];
    int c = blockIdx.x, t = threadIdx.x;
    row[t] = y1[(size_t)c * 512 + t];
    row[t + 256] = y1[(size_t)c * 512 + t + 256];
    __syncthreads();
    float acc = 0.f;
    #pragma unroll 4
    for (int o = 0; o < 512; o += 4) {
        float4 w4 = *(const float4*)(W2 + (size_t)t * 512 + o);
        float4 r4 = *(const float4*)(&row[o]);
        acc += w4.x * r4.x + w4.y * r4.y + w4.z * r4.z + w4.w * r4.w;
    }
    out[(size_t)c * 256 + t] = acc + b2[t];
}

extern "C" void kernel_launch(void* const* d_in, const int* in_sizes, int n_in,
                              void* d_out, int out_size, void* d_ws, size_t ws_size,
                              hipStream_t stream) {
    const float* x   = (const float*)d_in[0];
    const int*   adj = (const int*)d_in[1];
    const float* W   = (const float*)d_in[2];
    const float* a1  = (const float*)d_in[3];
    const float* a2  = (const float*)d_in[4];
    const float* Wo  = (const float*)d_in[5];
    const float* ao1 = (const float*)d_in[6];
    const float* ao2 = (const float*)d_in[7];
    const float* W1  = (const float*)d_in[8];
    const float* b1  = (const float*)d_in[9];
    const float* W2  = (const float*)d_in[10];
    const float* b2  = (const float*)d_in[11];
    float* out = (float*)d_out;

    char* ws = (char*)d_ws;
    size_t off = 0;
    auto alloc = [&](size_t bytes) {
        void* p = ws + off;
        off += (bytes + 255) & ~(size_t)255;
        return p;
    };
    u64*     mb2    = (u64*)alloc((size_t)N_NODES * 64 * 8);
    u16*     xB     = (u16*)alloc((size_t)N_NODES * FIN * 2);
    u16*     WBt    = (u16*)alloc((size_t)NHEAD * DHEAD * FIN * 2);
    u16*     WoBt   = (u16*)alloc((size_t)DHEAD * FIN * 2);
    u16*     W1B    = (u16*)alloc((size_t)512 * N_NODES * 2);
    u16*     WhB    = (u16*)alloc((size_t)NHEAD * DHEAD * N_NODES * 2);
    u16*     WhoB   = (u16*)alloc((size_t)DHEAD * N_NODES * 2);
    u16*     hB     = (u16*)alloc((size_t)N_NODES * 512 * 2);
    float*   part8  = (float*)alloc((size_t)2 * N_NODES * 512 * 4);   // 16 MB
    float*   den8   = (float*)alloc((size_t)2 * 8 * N_NODES * 4);
    float*   partT1 = (float*)alloc((size_t)8 * 64 * N_NODES * 4);    // 8 MB
    float*   den1   = (float*)alloc((size_t)8 * N_NODES * 4);
    u16*     lsT    = (u16*)alloc((size_t)64 * N_NODES * 2);
    float*   part   = (float*)alloc((size_t)16 * 64 * 512 * 4);
    float*   f1b    = (float*)alloc((size_t)9 * N_NODES * 4);
    float*   f2b    = (float*)alloc((size_t)9 * N_NODES * 4);
    unsigned* gmk   = (unsigned*)alloc(16 * 4);
    float4*  rowc   = (float4*)alloc((size_t)9 * N_NODES * 16);
    float2*  uvb    = (float2*)alloc((size_t)9 * N_NODES * 8);
    float*   y1     = (float*)alloc((size_t)64 * 512 * 4);
    (void)ws_size; (void)in_sizes; (void)n_in; (void)out_size;

    pack_mask<<<1024, 256, 0, stream>>>(adj, mb2, gmk);
    cvt4<<<(N_NODES * FIN / 4 + 255) / 256, 256, 0, stream>>>(x, xB, N_NODES * FIN / 4);
    cvt4<<<(512 * N_NODES / 4 + 255) / 256, 256, 0, stream>>>(W1, W1B, 512 * N_NODES / 4);
    to_bf16_T<<<dim3(8, 8), 256, 0, stream>>>(W, 64, (size_t)FIN * DHEAD, WBt,
                                              (size_t)DHEAD * FIN, FIN);
    to_bf16_T<<<dim3(8, 1), 256, 0, stream>>>(Wo, 64, 0, WoBt, 0, FIN);
    // layer 1
    gemm_fused<<<dim3(8, 64), 256, 0, stream>>>(xB, FIN, WBt, FIN, a1, a2,
                                                WhB, f1b, f2b, gmk, FIN);
    coefk<<<dim3(16, 8), 256, 0, stream>>>(f1b, f2b, gmk, rowc, uvb);
    attn_v4<8, 32, 2, 1><<<(N_NODES / 32) * 2 * 8, 256, 0, stream>>>(
        WhB, uvb, rowc, mb2, part8, den8);
    combine8<<<N_NODES * 512 / 4 / 256, 256, 0, stream>>>(part8, den8, hB);
    // layer 2
    gemm_fused<<<dim3(1, 64), 256, 0, stream>>>(hB, 512, WoBt, FIN, ao1, ao2,
                                                WhoB, f1b + (size_t)8 * N_NODES,
                                                f2b + (size_t)8 * N_NODES, gmk + 8, FIN);
    coefk<<<dim3(16, 1), 256, 0, stream>>>(f1b + (size_t)8 * N_NODES,
                                           f2b + (size_t)8 * N_NODES, gmk + 8,
                                           rowc + (size_t)8 * N_NODES,
                                           uvb + (size_t)8 * N_NODES);
    attn_v4<1, 32, 8, 3><<<(N_NODES / 32) * 8, 256, 0, stream>>>(
        WhoB, uvb + (size_t)8 * N_NODES, rowc + (size_t)8 * N_NODES, mb2, partT1, den1);
    combine1_lsm<<<64, 256, 0, stream>>>(partT1, den1, lsT);
    // MLP head
    mlp1_mfma<<<128, 256, 0, stream>>>(lsT, W1B, part);
    mlp1_fin<<<128, 256, 0, stream>>>(part, b1, y1);
    mlp2<<<64, 256, 0, stream>>>(y1, W2, b2, out);
}

// Round 9
// 214.405 us; speedup vs baseline: 1.0404x; 1.0404x over previous
//
#include <hip/hip_runtime.h>
#include <hip/hip_bf16.h>
#include <math.h>

// GAT forward. N=4096, Fin=512, H=8, D=64, C=64.
// Round 9: revert attention to round-7 attn_v3 (round-8 pair-packing caused
// 4.2M LDS write conflicts + 2x L2 B-traffic). Fix round-7's real limiter
// (32% occupancy): JSPLIT 2->4 on attn8 (2048 blocks = 8/CU), attn1 ROWS=32
// JSPLIT=8 (1024 blocks). B L2-traffic unchanged (depends on row-blocks only).
// Fewer launches: fused cvt4 pair, fused weight transposes, fused mlp1_fin+mlp2.

#define N_NODES 4096
#define FIN 512
#define NHEAD 8
#define DHEAD 64
#define NCLS 64
#define NW 64

typedef unsigned short u16;
typedef unsigned long long u64;
typedef __attribute__((ext_vector_type(8))) short bf16x8;
typedef __attribute__((ext_vector_type(4))) float f32x4;

__device__ __forceinline__ float lrelu02(float x) { return x > 0.f ? x : 0.2f * x; }
__device__ __forceinline__ u16 bf16u(float x) {
    __hip_bfloat16 h = __float2bfloat16(x);
    return __builtin_bit_cast(unsigned short, h);
}
__device__ __forceinline__ f32x4 mfma16(bf16x8 a, bf16x8 b, f32x4 c) {
    return __builtin_amdgcn_mfma_f32_16x16x32_bf16(a, b, c, 0, 0, 0);
}
__device__ __forceinline__ unsigned fkey(float f) {
    unsigned u = __builtin_bit_cast(unsigned, f);
    return (u & 0x80000000u) ? ~u : (u | 0x80000000u);
}
__device__ __forceinline__ float funkey(unsigned k) {
    unsigned u = (k & 0x80000000u) ? (k ^ 0x80000000u) : ~k;
    return __builtin_bit_cast(float, u);
}

// ---------------- adjacency -> bitmask (+ gmax key init) ----------------
__global__ void pack_mask(const int* __restrict__ adj, u64* __restrict__ mb,
                          unsigned* __restrict__ gmk) {
    if (blockIdx.x == 0 && threadIdx.x < 16) gmk[threadIdx.x] = 0u;
    int nwaves = (gridDim.x * blockDim.x) >> 6;
    int wid = (blockIdx.x * blockDim.x + threadIdx.x) >> 6;
    int lane = threadIdx.x & 63;
    for (int w = wid; w < N_NODES * NW; w += nwaves) {
        int i = w >> 6, wc = w & 63;
        int j = (wc << 6) | lane;
        u64 m = __ballot(adj[(size_t)i * N_NODES + j] > 0);
        if (lane == 0) mb[w] = m;
    }
}

// ---------------- fp32 -> bf16 flat convert, two buffers in one launch -------
__global__ void cvt4b(const float* __restrict__ sa, u16* __restrict__ da, int n4a,
                      const float* __restrict__ sb, u16* __restrict__ db, int n4b) {
    int i = blockIdx.x * blockDim.x + threadIdx.x;
    const float* s;
    u16* d;
    if (i < n4a) { s = sa; d = da; }
    else { i -= n4a; if (i >= n4b) return; s = sb; d = db; }
    float4 v = ((const float4*)s)[i];
    ushort4 o = {bf16u(v.x), bf16u(v.y), bf16u(v.z), bf16u(v.w)};
    ((ushort4*)d)[i] = o;
}

// ---------------- W[8][512][64] + Wo[512][64] -> bf16 transposed [d][k] -------
__global__ __launch_bounds__(256) void wT9(
    const float* __restrict__ W, const float* __restrict__ Wo,
    u16* __restrict__ WBt, u16* __restrict__ WoBt) {
    __shared__ alignas(16) u16 T[64][72];
    const int y = blockIdx.y;
    const float* src = (y < 8) ? W + (size_t)y * FIN * DHEAD : Wo;
    u16* d = (y < 8) ? WBt + (size_t)y * DHEAD * FIN : WoBt;
    const int j0 = blockIdx.x * 64;
    const int t = threadIdx.x;
    const int row = t & 63, g = t >> 6;
    #pragma unroll
    for (int k = 0; k < 16; k += 4) {
        float4 v = *(const float4*)(src + (size_t)(j0 + row) * 64 + g * 16 + k);
        T[g * 16 + k + 0][row] = bf16u(v.x);
        T[g * 16 + k + 1][row] = bf16u(v.y);
        T[g * 16 + k + 2][row] = bf16u(v.z);
        T[g * 16 + k + 3][row] = bf16u(v.w);
    }
    __syncthreads();
    const int dd = t >> 2, jc = (t & 3) * 16;
    *(uint4*)(d + (size_t)dd * FIN + j0 + jc) = *(const uint4*)&T[dd][jc];
    *(uint4*)(d + (size_t)dd * FIN + j0 + jc + 8) = *(const uint4*)&T[dd][jc + 8];
}

// ---------------- fused MFMA GEMM (x@W / h@Wo + f1/f2 + gmax + bf16-T out) ----
__global__ __launch_bounds__(256) void gemm_fused(
    const u16* __restrict__ A, int lda, const u16* __restrict__ Bt, int ldb,
    const float* __restrict__ a1a, const float* __restrict__ a2a,
    u16* __restrict__ WhBT, float* __restrict__ f1o, float* __restrict__ f2o,
    unsigned* __restrict__ gmk, int K) {
    __shared__ alignas(16) u16 T[64][72];
    const int t = threadIdx.x, lane = t & 63, wv = t >> 6;
    const int c16 = lane & 15, kg = lane >> 4;
    const int h = blockIdx.x;
    const int bm = blockIdx.y * 64;
    const u16* Ap = A + (size_t)(bm + wv * 16 + c16) * lda + kg * 8;
    const u16* Bp = Bt + (size_t)(h * 64 + c16) * ldb + kg * 8;
    f32x4 acc[4] = {};
    #pragma unroll 4
    for (int k0 = 0; k0 < K; k0 += 32) {
        bf16x8 a = *(const bf16x8*)(Ap + k0);
        #pragma unroll
        for (int ct = 0; ct < 4; ++ct) {
            bf16x8 b = *(const bf16x8*)(Bp + (size_t)ct * 16 * ldb + k0);
            acc[ct] = mfma16(a, b, acc[ct]);
        }
    }
    float a1v[4], a2v[4];
    #pragma unroll
    for (int ct = 0; ct < 4; ++ct) {
        a1v[ct] = a1a[h * 64 + ct * 16 + c16];
        a2v[ct] = a2a[h * 64 + ct * 16 + c16];
    }
    float mx = -1e30f;
    #pragma unroll
    for (int r = 0; r < 4; ++r) {
        float s1 = 0.f, s2 = 0.f;
        int rl = wv * 16 + kg * 4 + r;
        #pragma unroll
        for (int ct = 0; ct < 4; ++ct) {
            float v = acc[ct][r];
            s1 = fmaf(v, a1v[ct], s1);
            s2 = fmaf(v, a2v[ct], s2);
            T[ct * 16 + c16][rl] = bf16u(v);
        }
        #pragma unroll
        for (int off = 1; off < 16; off <<= 1) {
            s1 += __shfl_xor(s1, off, 64);
            s2 += __shfl_xor(s2, off, 64);
        }
        if (c16 == 0) {
            f1o[(size_t)h * N_NODES + bm + rl] = s1;
            f2o[(size_t)h * N_NODES + bm + rl] = s2;
        }
        mx = fmaxf(mx, s2);
    }
    mx = fmaxf(mx, __shfl_xor(mx, 16, 64));
    mx = fmaxf(mx, __shfl_xor(mx, 32, 64));
    if (lane == 0) atomicMax(&gmk[h], fkey(mx));
    __syncthreads();
    const int dd = t >> 2, jc = (t & 3) * 16;
    u16* dst = WhBT + (size_t)(h * 64 + dd) * N_NODES + bm;
    *(uint4*)(dst + jc) = *(const uint4*)&T[dd][jc];
    *(uint4*)(dst + jc + 8) = *(const uint4*)&T[dd][jc + 8];
}

// ---------------- per-row / per-col softmax coefficients ----------------
__global__ void coefk(const float* __restrict__ f1, const float* __restrict__ f2,
                      const unsigned* __restrict__ gmk, float4* __restrict__ rowc,
                      float2* __restrict__ uv) {
    int h = blockIdx.y;
    int i = blockIdx.x * 256 + threadIdx.x;
    float g = funkey(gmk[h]);
    float a = f1[(size_t)h * N_NODES + i];
    float s = a + g;
    float M = lrelu02(s);
    rowc[(size_t)h * N_NODES + i] = make_float4(__expf(s - M), __expf(0.2f * s - M), 0.f, 0.f);
    float b = f2[(size_t)h * N_NODES + i] - g;
    uv[(size_t)h * N_NODES + i] = make_float2(__expf(b), __expf(0.2f * b));
}

// ---------------- attention v3 (round-7 structure): prefetch, j-split --------
// OUTF 1: fp32 row-major partial [js][4096][512] (NH=8)
// OUTF 3: fp32 transposed partial [js][64][4096]  (NH=1)
template <int NH, int ROWS, int JSPLIT, int OUTF>
__global__ __launch_bounds__(256) void attn_v3(
    const u16* __restrict__ WhB, const float2* __restrict__ uv,
    const float4* __restrict__ rowc, const u64* __restrict__ mb,
    float* __restrict__ outp, float* __restrict__ denP) {
    constexpr int NQ = ROWS / 4;
    constexpr int NMT = ROWS / 16;
    constexpr int NJT = (N_NODES / 64) / JSPLIT;
    __shared__ alignas(16) u16 pS[2][ROWS][64];
    __shared__ float Tof[(OUTF == 3) ? 64 * (ROWS + 1) : 1];
    const int b = blockIdx.x;
    int h, ib, js;
    if (NH == 8) { h = b & 7; int r = b >> 3; js = r % JSPLIT; ib = r / JSPLIT; }
    else { h = 0; js = b % JSPLIT; ib = b / JSPLIT; }
    const int i0 = ib * ROWS;
    const int jt0 = js * NJT;
    const int t = threadIdx.x, lane = t & 63, wv = t >> 6;
    const int wv_u = __builtin_amdgcn_readfirstlane(wv);

    const float2* __restrict__ uvp = uv + (size_t)h * N_NODES;
    const float4* __restrict__ rcp = rowc + (size_t)h * N_NODES;
    const u64* __restrict__ mbp = mb + (size_t)(i0 + wv_u) * NW + jt0;

    float Aq[NQ], Bq[NQ], den[NQ];
    #pragma unroll
    for (int q = 0; q < NQ; ++q) {
        float4 rc = rcp[i0 + q * 4 + wv];
        Aq[q] = rc.x; Bq[q] = rc.y; den[q] = 0.f;
    }
    const int wcE = lane ^ (wv << 3);
    const int wcO = lane ^ ((wv + 4) << 3);
    const int kg = lane >> 4, c16 = lane & 15;
    const int ocol = wv * 16 + c16;
    const u16* bptr = WhB + ((size_t)h * 64 + ocol) * N_NODES + jt0 * 64 + kg * 8;
    const int sw8 = (c16 & 7) << 3;
    f32x4 acc[NMT] = {};

    bf16x8 b0 = *(const bf16x8*)(bptr);
    bf16x8 b1 = *(const bf16x8*)(bptr + 32);
    float2 uvv = uvp[jt0 * 64 + lane];
    u64 m[NQ];
    #pragma unroll
    for (int q = 0; q < NQ; ++q) m[q] = mbp[q * 4 * NW];

    for (int it = 0; it < NJT; ++it) {
        const int buf = it & 1;
        const int nit = (it + 1 < NJT) ? it + 1 : it;
        bf16x8 nb0 = *(const bf16x8*)(bptr + (size_t)nit * 64);
        bf16x8 nb1 = *(const bf16x8*)(bptr + (size_t)nit * 64 + 32);
        float2 nuv = uvp[(jt0 + nit) * 64 + lane];
        u64 nm[NQ];
        #pragma unroll
        for (int q = 0; q < NQ; ++q) nm[q] = mbp[q * 4 * NW + nit];
        #pragma unroll
        for (int q = 0; q < NQ; ++q) {
            unsigned wlo = __builtin_amdgcn_readfirstlane((unsigned)m[q]);
            unsigned whi = __builtin_amdgcn_readfirstlane((unsigned)(m[q] >> 32));
            u64 ws = ((u64)whi << 32) | wlo;
            float tv = fmaxf(Aq[q] * uvv.x, Bq[q] * uvv.y);
            float p;
            asm("v_cndmask_b32 %0, 0, %1, %2" : "=v"(p) : "v"(tv), "s"(ws));
            den[q] += p;
            pS[buf][q * 4 + wv][(q & 1) ? wcO : wcE] = bf16u(p);
        }
        __syncthreads();
        __builtin_amdgcn_s_setprio(1);
        #pragma unroll
        for (int mt = 0; mt < NMT; ++mt) {
            const u16* ap = &pS[buf][mt * 16 + c16][0];
            bf16x8 a0 = *(const bf16x8*)&ap[(kg * 8) ^ sw8];
            bf16x8 a1 = *(const bf16x8*)&ap[(32 + kg * 8) ^ sw8];
            acc[mt] = mfma16(a0, b0, acc[mt]);
            acc[mt] = mfma16(a1, b1, acc[mt]);
        }
        __builtin_amdgcn_s_setprio(0);
        b0 = nb0; b1 = nb1; uvv = nuv;
        #pragma unroll
        for (int q = 0; q < NQ; ++q) m[q] = nm[q];
    }

    #pragma unroll
    for (int q = 0; q < NQ; ++q) {
        float s = den[q];
        #pragma unroll
        for (int off = 32; off; off >>= 1) s += __shfl_xor(s, off, 64);
        den[q] = s;
    }

    if constexpr (OUTF == 1) {
        if (lane == 0) {
            #pragma unroll
            for (int q = 0; q < NQ; ++q)
                denP[(size_t)js * (8 * N_NODES) + (size_t)h * N_NODES + i0 + q * 4 + wv] = den[q];
        }
        float* dst = outp + (size_t)js * N_NODES * 512;
        #pragma unroll
        for (int mt = 0; mt < NMT; ++mt)
            #pragma unroll
            for (int r = 0; r < 4; ++r)
                dst[(size_t)(i0 + mt * 16 + kg * 4 + r) * 512 + h * 64 + ocol] = acc[mt][r];
    } else {
        if (lane == 0) {
            #pragma unroll
            for (int q = 0; q < NQ; ++q)
                denP[(size_t)js * N_NODES + i0 + q * 4 + wv] = den[q];
        }
        #pragma unroll
        for (int mt = 0; mt < NMT; ++mt)
            #pragma unroll
            for (int r = 0; r < 4; ++r)
                Tof[ocol * (ROWS + 1) + mt * 16 + kg * 4 + r] = acc[mt][r];
        __syncthreads();
        const int c = t >> 2, r0 = (t & 3) * 8;
        float* dst = outp + (size_t)js * 64 * N_NODES + (size_t)c * N_NODES + i0 + r0;
        float4 v0 = {Tof[c * (ROWS + 1) + r0 + 0], Tof[c * (ROWS + 1) + r0 + 1],
                     Tof[c * (ROWS + 1) + r0 + 2], Tof[c * (ROWS + 1) + r0 + 3]};
        float4 v1 = {Tof[c * (ROWS + 1) + r0 + 4], Tof[c * (ROWS + 1) + r0 + 5],
                     Tof[c * (ROWS + 1) + r0 + 6], Tof[c * (ROWS + 1) + r0 + 7]};
        *(float4*)(dst) = v0;
        *(float4*)(dst + 4) = v1;
    }
}

// ---------------- combine attn8 partials (4-way) -> bf16 hB ----------------
__global__ __launch_bounds__(256) void combine8(
    const float* __restrict__ part, const float* __restrict__ denp,
    u16* __restrict__ hB) {
    const int t4 = (blockIdx.x * 256 + threadIdx.x) * 4;
    const int i = t4 >> 9, c = t4 & 511, h = c >> 6;
    float4 s = {0.f, 0.f, 0.f, 0.f};
    float d = 0.f;
    #pragma unroll
    for (int js = 0; js < 4; ++js) {
        float4 p = *(const float4*)(part + (size_t)js * N_NODES * 512 + t4);
        s.x += p.x; s.y += p.y; s.z += p.z; s.w += p.w;
        d += denp[(size_t)js * (8 * N_NODES) + h * N_NODES + i];
    }
    float inv = d > 0.f ? 1.f / d : 0.f;
    float v[4] = {s.x * inv, s.y * inv, s.z * inv, s.w * inv};
    ushort4 o;
    #pragma unroll
    for (int k = 0; k < 4; ++k) {
        float e = v[k] > 0.f ? v[k] : expm1f(v[k]);
        ((u16*)&o)[k] = bf16u(e);
    }
    *(ushort4*)(hB + t4) = o;
}

// ---------------- combine attn1 partials (8-way) + ELU + log_softmax ---------
__global__ __launch_bounds__(256) void combine1_lsm(
    const float* __restrict__ partT, const float* __restrict__ denp,
    u16* __restrict__ lsT) {
    __shared__ float vb[N_NODES];
    __shared__ float r[256];
    const int c = blockIdx.x, t = threadIdx.x;
    float m = -1e30f;
    for (int i = t * 4; i < N_NODES; i += 1024) {
        float4 s = {0.f, 0.f, 0.f, 0.f}, d = {0.f, 0.f, 0.f, 0.f};
        #pragma unroll
        for (int js = 0; js < 8; ++js) {
            float4 pv = *(const float4*)(partT + (size_t)js * 64 * N_NODES +
                                         (size_t)c * N_NODES + i);
            float4 dv = *(const float4*)(denp + (size_t)js * N_NODES + i);
            s.x += pv.x; s.y += pv.y; s.z += pv.z; s.w += pv.w;
            d.x += dv.x; d.y += dv.y; d.z += dv.z; d.w += dv.w;
        }
        float vv[4] = {d.x > 0.f ? s.x / d.x : 0.f, d.y > 0.f ? s.y / d.y : 0.f,
                       d.z > 0.f ? s.z / d.z : 0.f, d.w > 0.f ? s.w / d.w : 0.f};
        #pragma unroll
        for (int k = 0; k < 4; ++k) {
            float e = vv[k] > 0.f ? vv[k] : expm1f(vv[k]);
            vb[i + k] = e;
            m = fmaxf(m, e);
        }
    }
    r[t] = m;
    __syncthreads();
    for (int s = 128; s; s >>= 1) {
        if (t < s) r[t] = fmaxf(r[t], r[t + s]);
        __syncthreads();
    }
    m = r[0];
    __syncthreads();
    float sum = 0.f;
    for (int i = t; i < N_NODES; i += 256) sum += __expf(vb[i] - m);
    r[t] = sum;
    __syncthreads();
    for (int s = 128; s; s >>= 1) {
        if (t < s) r[t] += r[t + s];
        __syncthreads();
    }
    float lse = m + __logf(r[0]);
    for (int i = t * 4; i < N_NODES; i += 1024) {
        ushort4 o = {bf16u(vb[i] - lse), bf16u(vb[i + 1] - lse),
                     bf16u(vb[i + 2] - lse), bf16u(vb[i + 3] - lse)};
        *(ushort4*)(lsT + (size_t)c * N_NODES + i) = o;
    }
}

// ---------------- mlp1: split-K MFMA  part[ks][64 c][512 o] ----------------
__global__ __launch_bounds__(256) void mlp1_mfma(
    const u16* __restrict__ lsT, const u16* __restrict__ W1B,
    float* __restrict__ part) {
    const int t = threadIdx.x, lane = t & 63, wv = t >> 6;
    const int c16 = lane & 15, kg = lane >> 4;
    const int ks = blockIdx.x & 15;
    const int bn = (blockIdx.x >> 4) * 64;
    const int kb = ks * 256;
    const u16* Ap = lsT + (size_t)(wv * 16 + c16) * N_NODES + kb + kg * 8;
    const u16* Bp = W1B + (size_t)(bn + c16) * N_NODES + kb + kg * 8;
    f32x4 acc[4] = {};
    #pragma unroll
    for (int k0 = 0; k0 < 256; k0 += 32) {
        bf16x8 a = *(const bf16x8*)(Ap + k0);
        #pragma unroll
        for (int ct = 0; ct < 4; ++ct) {
            bf16x8 b = *(const bf16x8*)(Bp + (size_t)ct * 16 * N_NODES + k0);
            acc[ct] = mfma16(a, b, acc[ct]);
        }
    }
    float* dst = part + (size_t)ks * 64 * 512;
    #pragma unroll
    for (int ct = 0; ct < 4; ++ct)
        #pragma unroll
        for (int r = 0; r < 4; ++r)
            dst[(size_t)(wv * 16 + kg * 4 + r) * 512 + bn + ct * 16 + c16] = acc[ct][r];
}

// ---------------- fused: reduce split-K + bias + leaky, then y @ W2^T --------
__global__ __launch_bounds__(256) void mlp2f(
    const float* __restrict__ part, const float* __restrict__ b1,
    const float* __restrict__ W2, const float* __restrict__ b2,
    float* __restrict__ out) {
    __shared__ alignas(16) float row[512];
    const int c = blockIdx.x, t = threadIdx.x;
    #pragma unroll
    for (int half = 0; half < 2; ++half) {
        int o = t + half * 256;
        float s = 0.f;
        #pragma unroll
        for (int ks = 0; ks < 16; ++ks)
            s += part[(size_t)ks * 32768 + (size_t)c * 512 + o];
        s += b1[o];
        row[o] = s > 0.f ? s : 0.1f * s;
    }
    __syncthreads();
    float acc = 0.f;
    #pragma unroll 4
    for (int o = 0; o < 512; o += 4) {
        float4 w4 = *(const float4*)(W2 + (size_t)t * 512 + o);
        float4 r4 = *(const float4*)(&row[o]);
        acc += w4.x * r4.x + w4.y * r4.y + w4.z * r4.z + w4.w * r4.w;
    }
    out[(size_t)c * 256 + t] = acc + b2[t];
}

extern "C" void kernel_launch(void* const* d_in, const int* in_sizes, int n_in,
                              void* d_out, int out_size, void* d_ws, size_t ws_size,
                              hipStream_t stream) {
    const float* x   = (const float*)d_in[0];
    const int*   adj = (const int*)d_in[1];
    const float* W   = (const float*)d_in[2];
    const float* a1  = (const float*)d_in[3];
    const float* a2  = (const float*)d_in[4];
    const float* Wo  = (const float*)d_in[5];
    const float* ao1 = (const float*)d_in[6];
    const float* ao2 = (const float*)d_in[7];
    const float* W1  = (const float*)d_in[8];
    const float* b1  = (const float*)d_in[9];
    const float* W2  = (const float*)d_in[10];
    const float* b2  = (const float*)d_in[11];
    float* out = (float*)d_out;

    char* ws = (char*)d_ws;
    size_t off = 0;
    auto alloc = [&](size_t bytes) {
        void* p = ws + off;
        off += (bytes + 255) & ~(size_t)255;
        return p;
    };
    u64*     mb     = (u64*)alloc((size_t)N_NODES * NW * 8);
    u16*     xB     = (u16*)alloc((size_t)N_NODES * FIN * 2);
    u16*     WBt    = (u16*)alloc((size_t)NHEAD * DHEAD * FIN * 2);
    u16*     WoBt   = (u16*)alloc((size_t)DHEAD * FIN * 2);
    u16*     W1B    = (u16*)alloc((size_t)512 * N_NODES * 2);
    u16*     WhB    = (u16*)alloc((size_t)NHEAD * DHEAD * N_NODES * 2);
    u16*     WhoB   = (u16*)alloc((size_t)DHEAD * N_NODES * 2);
    u16*     hB     = (u16*)alloc((size_t)N_NODES * 512 * 2);
    float*   part8  = (float*)alloc((size_t)4 * N_NODES * 512 * 4);   // 32 MB
    float*   den8   = (float*)alloc((size_t)4 * 8 * N_NODES * 4);
    float*   f1b    = (float*)alloc((size_t)9 * N_NODES * 4);
    float*   f2b    = (float*)alloc((size_t)9 * N_NODES * 4);
    unsigned* gmk   = (unsigned*)alloc(16 * 4);
    float4*  rowc   = (float4*)alloc((size_t)9 * N_NODES * 16);
    float2*  uvb    = (float2*)alloc((size_t)9 * N_NODES * 8);
    // layer-2 scratch overlaid on part8 (dead after combine8)
    char*    ov     = (char*)part8;
    float*   partT1 = (float*)(ov);                                    // 8 MB
    float*   den1   = (float*)(ov + ((size_t)8 << 20));                // 128 KB
    u16*     lsT    = (u16*)(ov + ((size_t)8 << 20) + (256 << 10));    // 512 KB
    float*   part   = (float*)(ov + ((size_t)9 << 20));                // 2 MB
    (void)ws_size; (void)in_sizes; (void)n_in; (void)out_size;

    pack_mask<<<1024, 256, 0, stream>>>(adj, mb, gmk);
    cvt4b<<<(2 * N_NODES * FIN / 4 + 255) / 256, 256, 0, stream>>>(
        x, xB, N_NODES * FIN / 4, W1, W1B, 512 * N_NODES / 4);
    wT9<<<dim3(8, 9), 256, 0, stream>>>(W, Wo, WBt, WoBt);
    // layer 1
    gemm_fused<<<dim3(8, 64), 256, 0, stream>>>(xB, FIN, WBt, FIN, a1, a2,
                                                WhB, f1b, f2b, gmk, FIN);
    coefk<<<dim3(16, 8), 256, 0, stream>>>(f1b, f2b, gmk, rowc, uvb);
    attn_v3<8, 64, 4, 1><<<(N_NODES / 64) * 4 * 8, 256, 0, stream>>>(
        WhB, uvb, rowc, mb, part8, den8);
    combine8<<<N_NODES * 512 / 4 / 256, 256, 0, stream>>>(part8, den8, hB);
    // layer 2
    gemm_fused<<<dim3(1, 64), 256, 0, stream>>>(hB, 512, WoBt, FIN, ao1, ao2,
                                                WhoB, f1b + (size_t)8 * N_NODES,
                                                f2b + (size_t)8 * N_NODES, gmk + 8, FIN);
    coefk<<<dim3(16, 1), 256, 0, stream>>>(f1b + (size_t)8 * N_NODES,
                                           f2b + (size_t)8 * N_NODES, gmk + 8,
                                           rowc + (size_t)8 * N_NODES,
                                           uvb + (size_t)8 * N_NODES);
    attn_v3<1, 32, 8, 3><<<(N_NODES / 32) * 8, 256, 0, stream>>>(
        WhoB, uvb + (size_t)8 * N_NODES, rowc + (size_t)8 * N_NODES, mb, partT1, den1);
    combine1_lsm<<<64, 256, 0, stream>>>(partT1, den1, lsT);
    // MLP head
    mlp1_mfma<<<128, 256, 0, stream>>>(lsT, W1B, part);
    mlp2f<<<64, 256, 0, stream>>>(part, b1, W2, b2, out);
}

// Round 10
// 213.509 us; speedup vs baseline: 1.0448x; 1.0042x over previous
//
#include <hip/hip_runtime.h>
#include <hip/hip_bf16.h>
#include <math.h>

// GAT forward. N=4096, Fin=512, H=8, D=64, C=64.
// Round 10: attn_v5 = round-7 skeleton with per-entry instruction cuts:
//  - den via MFMA (ones B-fragment) -> kills per-entry den adds + end reduce
//  - wave-contiguous rows (wv*16+q) -> row coefs A/B s-loaded to SGPRs (frees
//    32 VGPRs), masks from TRANSPOSED mbT[jword][row] = 2 merged s_loads/tile
//    issued post-p-phase (latency hidden under barrier+MFMA)
//  - JSPLIT=2 (round-9's 4 doubled HBM writes for zero occupancy gain)
//  - attn1 ROWS 64 (halves B re-reads); prep kernel fuses pack/cvt/wT (-3 launches)

#define N_NODES 4096
#define FIN 512
#define NHEAD 8
#define DHEAD 64
#define NCLS 64

typedef unsigned short u16;
typedef unsigned long long u64;
typedef __attribute__((ext_vector_type(8))) short bf16x8;
typedef __attribute__((ext_vector_type(4))) float f32x4;

__device__ __forceinline__ float lrelu02(float x) { return x > 0.f ? x : 0.2f * x; }
__device__ __forceinline__ u16 bf16u(float x) {
    __hip_bfloat16 h = __float2bfloat16(x);
    return __builtin_bit_cast(unsigned short, h);
}
__device__ __forceinline__ f32x4 mfma16(bf16x8 a, bf16x8 b, f32x4 c) {
    return __builtin_amdgcn_mfma_f32_16x16x32_bf16(a, b, c, 0, 0, 0);
}
__device__ __forceinline__ unsigned fkey(float f) {
    unsigned u = __builtin_bit_cast(unsigned, f);
    return (u & 0x80000000u) ? ~u : (u | 0x80000000u);
}
__device__ __forceinline__ float funkey(unsigned k) {
    unsigned u = (k & 0x80000000u) ? (k ^ 0x80000000u) : ~k;
    return __builtin_bit_cast(float, u);
}

// ---------------- prep: pack adj -> mbT[jword][row], bf16 cvts, weight T -----
__global__ __launch_bounds__(256) void prep(
    const int* __restrict__ adj, u64* __restrict__ mbT, unsigned* __restrict__ gmk,
    const float* __restrict__ x, u16* __restrict__ xB,
    const float* __restrict__ W1, u16* __restrict__ W1B,
    const float* __restrict__ W, const float* __restrict__ Wo,
    u16* __restrict__ WBt, u16* __restrict__ WoBt) {
    __shared__ alignas(16) u16 T[64][72];
    const int bid = blockIdx.x, t = threadIdx.x;
    if (bid < 1024) {
        // pack_mask -> transposed layout
        if (bid == 0 && t < 16) gmk[t] = 0u;
        int nwaves = (1024 * 256) >> 6;
        int wid = (bid * 256 + t) >> 6;
        int lane = t & 63;
        for (int w = wid; w < N_NODES * 64; w += nwaves) {
            int i = w >> 6, wc = w & 63;
            int j = (wc << 6) | lane;
            u64 m = __ballot(adj[(size_t)i * N_NODES + j] > 0);
            if (lane == 0) mbT[(size_t)wc * N_NODES + i] = m;
        }
    } else if (bid < 5120) {
        // bf16 converts: x (512K quads) then W1 (512K quads)
        int i = (bid - 1024) * 256 + t;
        const float* s;
        u16* d;
        if (i < N_NODES * FIN / 4) { s = x; d = xB; }
        else { i -= N_NODES * FIN / 4; s = W1; d = W1B; }
        float4 v = ((const float4*)s)[i];
        ushort4 o = {bf16u(v.x), bf16u(v.y), bf16u(v.z), bf16u(v.w)};
        ((ushort4*)d)[i] = o;
    } else {
        // weight transposes: W[8][512][64] and Wo[512][64] -> [d][k] bf16
        int idx = bid - 5120;
        int y = idx >> 3, xb = idx & 7;
        const float* src = (y < 8) ? W + (size_t)y * FIN * DHEAD : Wo;
        u16* d = (y < 8) ? WBt + (size_t)y * DHEAD * FIN : WoBt;
        const int j0 = xb * 64;
        const int row = t & 63, g = t >> 6;
        #pragma unroll
        for (int k = 0; k < 16; k += 4) {
            float4 v = *(const float4*)(src + (size_t)(j0 + row) * 64 + g * 16 + k);
            T[g * 16 + k + 0][row] = bf16u(v.x);
            T[g * 16 + k + 1][row] = bf16u(v.y);
            T[g * 16 + k + 2][row] = bf16u(v.z);
            T[g * 16 + k + 3][row] = bf16u(v.w);
        }
        __syncthreads();
        const int dd = t >> 2, jc = (t & 3) * 16;
        *(uint4*)(d + (size_t)dd * FIN + j0 + jc) = *(const uint4*)&T[dd][jc];
        *(uint4*)(d + (size_t)dd * FIN + j0 + jc + 8) = *(const uint4*)&T[dd][jc + 8];
    }
}

// ---------------- fused MFMA GEMM (x@W / h@Wo + f1/f2 + gmax + bf16-T out) ----
__global__ __launch_bounds__(256) void gemm_fused(
    const u16* __restrict__ A, int lda, const u16* __restrict__ Bt, int ldb,
    const float* __restrict__ a1a, const float* __restrict__ a2a,
    u16* __restrict__ WhBT, float* __restrict__ f1o, float* __restrict__ f2o,
    unsigned* __restrict__ gmk, int K) {
    __shared__ alignas(16) u16 T[64][72];
    const int t = threadIdx.x, lane = t & 63, wv = t >> 6;
    const int c16 = lane & 15, kg = lane >> 4;
    const int h = blockIdx.x;
    const int bm = blockIdx.y * 64;
    const u16* Ap = A + (size_t)(bm + wv * 16 + c16) * lda + kg * 8;
    const u16* Bp = Bt + (size_t)(h * 64 + c16) * ldb + kg * 8;
    f32x4 acc[4] = {};
    #pragma unroll 4
    for (int k0 = 0; k0 < K; k0 += 32) {
        bf16x8 a = *(const bf16x8*)(Ap + k0);
        #pragma unroll
        for (int ct = 0; ct < 4; ++ct) {
            bf16x8 b = *(const bf16x8*)(Bp + (size_t)ct * 16 * ldb + k0);
            acc[ct] = mfma16(a, b, acc[ct]);
        }
    }
    float a1v[4], a2v[4];
    #pragma unroll
    for (int ct = 0; ct < 4; ++ct) {
        a1v[ct] = a1a[h * 64 + ct * 16 + c16];
        a2v[ct] = a2a[h * 64 + ct * 16 + c16];
    }
    float mx = -1e30f;
    #pragma unroll
    for (int r = 0; r < 4; ++r) {
        float s1 = 0.f, s2 = 0.f;
        int rl = wv * 16 + kg * 4 + r;
        #pragma unroll
        for (int ct = 0; ct < 4; ++ct) {
            float v = acc[ct][r];
            s1 = fmaf(v, a1v[ct], s1);
            s2 = fmaf(v, a2v[ct], s2);
            T[ct * 16 + c16][rl] = bf16u(v);
        }
        #pragma unroll
        for (int off = 1; off < 16; off <<= 1) {
            s1 += __shfl_xor(s1, off, 64);
            s2 += __shfl_xor(s2, off, 64);
        }
        if (c16 == 0) {
            f1o[(size_t)h * N_NODES + bm + rl] = s1;
            f2o[(size_t)h * N_NODES + bm + rl] = s2;
        }
        mx = fmaxf(mx, s2);
    }
    mx = fmaxf(mx, __shfl_xor(mx, 16, 64));
    mx = fmaxf(mx, __shfl_xor(mx, 32, 64));
    if (lane == 0) atomicMax(&gmk[h], fkey(mx));
    __syncthreads();
    const int dd = t >> 2, jc = (t & 3) * 16;
    u16* dst = WhBT + (size_t)(h * 64 + dd) * N_NODES + bm;
    *(uint4*)(dst + jc) = *(const uint4*)&T[dd][jc];
    *(uint4*)(dst + jc + 8) = *(const uint4*)&T[dd][jc + 8];
}

// ---------------- per-row / per-col softmax coefficients ----------------
__global__ void coefk(const float* __restrict__ f1, const float* __restrict__ f2,
                      const unsigned* __restrict__ gmk, float2* __restrict__ rowc,
                      float2* __restrict__ uv) {
    int h = blockIdx.y;
    int i = blockIdx.x * 256 + threadIdx.x;
    float g = funkey(gmk[h]);
    float a = f1[(size_t)h * N_NODES + i];
    float s = a + g;
    float M = lrelu02(s);
    rowc[(size_t)h * N_NODES + i] = make_float2(__expf(s - M), __expf(0.2f * s - M));
    float b = f2[(size_t)h * N_NODES + i] - g;
    uv[(size_t)h * N_NODES + i] = make_float2(__expf(b), __expf(0.2f * b));
}

// ---------------- attention v5 ----------------
// rows owned wave-contiguously (wv*16+q); coefs in SGPR; masks s-loaded from
// transposed mbT; den via MFMA with ones; 64-wide tiles, dbuf swizzled pS.
// OUTF 1: fp32 row-major partial [js][4096][512] (NH=8)
// OUTF 3: fp32 transposed partial [js][64][4096]  (NH=1)
template <int NH, int ROWS, int JSPLIT, int OUTF>
__global__ __launch_bounds__(256) void attn_v5(
    const u16* __restrict__ WhB, const float2* __restrict__ uv,
    const float2* __restrict__ rowc, const u64* __restrict__ mbT,
    float* __restrict__ outp, float* __restrict__ denP) {
    constexpr int NMT = ROWS / 16;
    constexpr int NJT = (N_NODES / 64) / JSPLIT;
    __shared__ alignas(16) u16 pS[2][ROWS][64];
    __shared__ float Tof[(OUTF == 3) ? 64 * (ROWS + 1) : 1];
    const int b = blockIdx.x;
    int h, ib, js;
    if (NH == 8) { h = b & 7; int r = b >> 3; js = r % JSPLIT; ib = r / JSPLIT; }
    else { h = 0; js = b % JSPLIT; ib = b / JSPLIT; }
    const int i0 = ib * ROWS;
    const int jt0 = js * NJT;
    const int t = threadIdx.x, lane = t & 63, wv = t >> 6;
    const int wv_u = __builtin_amdgcn_readfirstlane(wv);

    const float2* __restrict__ uvp = uv + (size_t)h * N_NODES;

    // row coefficients: wave-uniform -> SGPRs, loaded once
    float Aq[16], Bq[16];
    {
        const float2* rcw = rowc + (size_t)h * N_NODES + i0 + wv_u * 16;
        #pragma unroll
        for (int q = 0; q < 16; ++q) {
            float2 rc = rcw[q];
            Aq[q] = __builtin_amdgcn_readfirstlane(rc.x);
            Bq[q] = __builtin_amdgcn_readfirstlane(rc.y);
        }
    }

    const int kg = lane >> 4, c16 = lane & 15;
    const int ocol = wv * 16 + c16;
    const u16* bptr = WhB + ((size_t)h * 64 + ocol) * N_NODES + jt0 * 64 + kg * 8;
    const int sw8 = (c16 & 7) << 3;
    f32x4 acc[NMT] = {};
    f32x4 acc_d[NMT] = {};
    bf16x8 ones;
    #pragma unroll
    for (int i = 0; i < 8; ++i) ones[i] = (short)0x3F80;

    // prologue: tile-0 operands
    bf16x8 b0 = *(const bf16x8*)(bptr);
    bf16x8 b1 = *(const bf16x8*)(bptr + 32);
    float2 uvv = uvp[jt0 * 64 + lane];
    u64 m[16];
    {
        const u64* mrow = mbT + (size_t)jt0 * N_NODES + i0 + wv_u * 16;
        #pragma unroll
        for (int q = 0; q < 16; ++q) m[q] = mrow[q];
    }

    for (int it = 0; it < NJT; ++it) {
        const int buf = it & 1;
        const int nit = (it + 1 < NJT) ? it + 1 : it;
        bf16x8 nb0 = *(const bf16x8*)(bptr + (size_t)nit * 64);
        bf16x8 nb1 = *(const bf16x8*)(bptr + (size_t)nit * 64 + 32);
        float2 nuv = uvp[(jt0 + nit) * 64 + lane];
        // p-phase (rows wv*16+q, col=lane)
        #pragma unroll
        for (int q = 0; q < 16; ++q) {
            unsigned wlo = __builtin_amdgcn_readfirstlane((unsigned)m[q]);
            unsigned whi = __builtin_amdgcn_readfirstlane((unsigned)(m[q] >> 32));
            u64 ws = ((u64)whi << 32) | wlo;
            float tv = fmaxf(Aq[q] * uvv.x, Bq[q] * uvv.y);
            float p;
            asm("v_cndmask_b32 %0, 0, %1, %2" : "=v"(p) : "v"(tv), "s"(ws));
            pS[buf][wv * 16 + q][lane ^ ((q & 7) << 3)] = bf16u(p);
        }
        // masks dead: issue next-tile scalar loads (drain under barrier+MFMA)
        {
            const u64* mrow = mbT + (size_t)(jt0 + nit) * N_NODES + i0 + wv_u * 16;
            #pragma unroll
            for (int q = 0; q < 16; ++q) m[q] = mrow[q];
        }
        __syncthreads();
        __builtin_amdgcn_s_setprio(1);
        #pragma unroll
        for (int mt = 0; mt < NMT; ++mt) {
            const u16* ap = &pS[buf][mt * 16 + c16][0];
            bf16x8 a0 = *(const bf16x8*)&ap[(kg * 8) ^ sw8];
            bf16x8 a1 = *(const bf16x8*)&ap[(32 + kg * 8) ^ sw8];
            acc[mt] = mfma16(a0, b0, acc[mt]);
            acc[mt] = mfma16(a1, b1, acc[mt]);
            acc_d[mt] = mfma16(a0, ones, acc_d[mt]);
            acc_d[mt] = mfma16(a1, ones, acc_d[mt]);
        }
        __builtin_amdgcn_s_setprio(0);
        b0 = nb0; b1 = nb1; uvv = nuv;
    }

    if constexpr (OUTF == 1) {
        if (wv == 0 && c16 == 0) {
            #pragma unroll
            for (int mt = 0; mt < NMT; ++mt)
                #pragma unroll
                for (int r = 0; r < 4; ++r)
                    denP[(size_t)js * (8 * N_NODES) + (size_t)h * N_NODES +
                         i0 + mt * 16 + kg * 4 + r] = acc_d[mt][r];
        }
        float* dst = outp + (size_t)js * N_NODES * 512;
        #pragma unroll
        for (int mt = 0; mt < NMT; ++mt)
            #pragma unroll
            for (int r = 0; r < 4; ++r)
                dst[(size_t)(i0 + mt * 16 + kg * 4 + r) * 512 + h * 64 + ocol] = acc[mt][r];
    } else {
        if (wv == 0 && c16 == 0) {
            #pragma unroll
            for (int mt = 0; mt < NMT; ++mt)
                #pragma unroll
                for (int r = 0; r < 4; ++r)
                    denP[(size_t)js * N_NODES + i0 + mt * 16 + kg * 4 + r] = acc_d[mt][r];
        }
        #pragma unroll
        for (int mt = 0; mt < NMT; ++mt)
            #pragma unroll
            for (int r = 0; r < 4; ++r)
                Tof[ocol * (ROWS + 1) + mt * 16 + kg * 4 + r] = acc[mt][r];
        __syncthreads();
        const int c = t >> 2, r0 = (t & 3) * 16;
        float* dst = outp + (size_t)js * 64 * N_NODES + (size_t)c * N_NODES + i0 + r0;
        #pragma unroll
        for (int k = 0; k < 16; k += 4) {
            float4 v = {Tof[c * (ROWS + 1) + r0 + k + 0], Tof[c * (ROWS + 1) + r0 + k + 1],
                        Tof[c * (ROWS + 1) + r0 + k + 2], Tof[c * (ROWS + 1) + r0 + k + 3]};
            *(float4*)(dst + k) = v;
        }
    }
}

// ---------------- combine attn8 partials (2-way) -> bf16 hB ----------------
__global__ __launch_bounds__(256) void combine8(
    const float* __restrict__ part, const float* __restrict__ denp,
    u16* __restrict__ hB) {
    const int t4 = (blockIdx.x * 256 + threadIdx.x) * 4;
    const int i = t4 >> 9, c = t4 & 511, h = c >> 6;
    float4 p0 = *(const float4*)(part + t4);
    float4 p1 = *(const float4*)(part + (size_t)N_NODES * 512 + t4);
    float d = denp[h * N_NODES + i] + denp[8 * N_NODES + h * N_NODES + i];
    float inv = d > 0.f ? 1.f / d : 0.f;
    float v[4] = {(p0.x + p1.x) * inv, (p0.y + p1.y) * inv,
                  (p0.z + p1.z) * inv, (p0.w + p1.w) * inv};
    ushort4 o;
    #pragma unroll
    for (int k = 0; k < 4; ++k) {
        float e = v[k] > 0.f ? v[k] : expm1f(v[k]);
        ((u16*)&o)[k] = bf16u(e);
    }
    *(ushort4*)(hB + t4) = o;
}

// ---------------- combine attn1 partials (8-way) + ELU + log_softmax ---------
__global__ __launch_bounds__(1024) void combine1_lsm(
    const float* __restrict__ partT, const float* __restrict__ denp,
    u16* __restrict__ lsT) {
    __shared__ float vb[N_NODES];
    __shared__ float r[1024];
    const int c = blockIdx.x, t = threadIdx.x;
    const int i = t * 4;
    float4 s = {0.f, 0.f, 0.f, 0.f}, d = {0.f, 0.f, 0.f, 0.f};
    #pragma unroll
    for (int js = 0; js < 8; ++js) {
        float4 pv = *(const float4*)(partT + (size_t)js * 64 * N_NODES +
                                     (size_t)c * N_NODES + i);
        float4 dv = *(const float4*)(denp + (size_t)js * N_NODES + i);
        s.x += pv.x; s.y += pv.y; s.z += pv.z; s.w += pv.w;
        d.x += dv.x; d.y += dv.y; d.z += dv.z; d.w += dv.w;
    }
    float vv[4] = {d.x > 0.f ? s.x / d.x : 0.f, d.y > 0.f ? s.y / d.y : 0.f,
                   d.z > 0.f ? s.z / d.z : 0.f, d.w > 0.f ? s.w / d.w : 0.f};
    float m = -1e30f;
    #pragma unroll
    for (int k = 0; k < 4; ++k) {
        float e = vv[k] > 0.f ? vv[k] : expm1f(vv[k]);
        vb[i + k] = e;
        m = fmaxf(m, e);
    }
    r[t] = m;
    __syncthreads();
    for (int st = 512; st; st >>= 1) {
        if (t < st) r[t] = fmaxf(r[t], r[t + st]);
        __syncthreads();
    }
    m = r[0];
    __syncthreads();
    float sum = 0.f;
    for (int ii = t; ii < N_NODES; ii += 1024) sum += __expf(vb[ii] - m);
    r[t] = sum;
    __syncthreads();
    for (int st = 512; st; st >>= 1) {
        if (t < st) r[t] += r[t + st];
        __syncthreads();
    }
    float lse = m + __logf(r[0]);
    ushort4 o = {bf16u(vb[i] - lse), bf16u(vb[i + 1] - lse),
                 bf16u(vb[i + 2] - lse), bf16u(vb[i + 3] - lse)};
    *(ushort4*)(lsT + (size_t)c * N_NODES + i) = o;
}

// ---------------- mlp1: split-K MFMA  part[ks][64 c][512 o] ----------------
__global__ __launch_bounds__(256) void mlp1_mfma(
    const u16* __restrict__ lsT, const u16* __restrict__ W1B,
    float* __restrict__ part) {
    const int t = threadIdx.x, lane = t & 63, wv = t >> 6;
    const int c16 = lane & 15, kg = lane >> 4;
    const int ks = blockIdx.x & 15;
    const int bn = (blockIdx.x >> 4) * 64;
    const int kb = ks * 256;
    const u16* Ap = lsT + (size_t)(wv * 16 + c16) * N_NODES + kb + kg * 8;
    const u16* Bp = W1B + (size_t)(bn + c16) * N_NODES + kb + kg * 8;
    f32x4 acc[4] = {};
    #pragma unroll
    for (int k0 = 0; k0 < 256; k0 += 32) {
        bf16x8 a = *(const bf16x8*)(Ap + k0);
        #pragma unroll
        for (int ct = 0; ct < 4; ++ct) {
            bf16x8 b = *(const bf16x8*)(Bp + (size_t)ct * 16 * N_NODES + k0);
            acc[ct] = mfma16(a, b, acc[ct]);
        }
    }
    float* dst = part + (size_t)ks * 64 * 512;
    #pragma unroll
    for (int ct = 0; ct < 4; ++ct)
        #pragma unroll
        for (int r = 0; r < 4; ++r)
            dst[(size_t)(wv * 16 + kg * 4 + r) * 512 + bn + ct * 16 + c16] = acc[ct][r];
}

// ---------------- fused: reduce split-K + bias + leaky, then y @ W2^T --------
__global__ __launch_bounds__(256) void mlp2f(
    const float* __restrict__ part, const float* __restrict__ b1,
    const float* __restrict__ W2, const float* __restrict__ b2,
    float* __restrict__ out) {
    __shared__ alignas(16) float row[512];
    const int c = blockIdx.x, t = threadIdx.x;
    #pragma unroll
    for (int half = 0; half < 2; ++half) {
        int o = t + half * 256;
        float s = 0.f;
        #pragma unroll
        for (int ks = 0; ks < 16; ++ks)
            s += part[(size_t)ks * 32768 + (size_t)c * 512 + o];
        s += b1[o];
        row[o] = s > 0.f ? s : 0.1f * s;
    }
    __syncthreads();
    float acc = 0.f;
    #pragma unroll 4
    for (int o = 0; o < 512; o += 4) {
        float4 w4 = *(const float4*)(W2 + (size_t)t * 512 + o);
        float4 r4 = *(const float4*)(&row[o]);
        acc += w4.x * r4.x + w4.y * r4.y + w4.z * r4.z + w4.w * r4.w;
    }
    out[(size_t)c * 256 + t] = acc + b2[t];
}

extern "C" void kernel_launch(void* const* d_in, const int* in_sizes, int n_in,
                              void* d_out, int out_size, void* d_ws, size_t ws_size,
                              hipStream_t stream) {
    const float* x   = (const float*)d_in[0];
    const int*   adj = (const int*)d_in[1];
    const float* W   = (const float*)d_in[2];
    const float* a1  = (const float*)d_in[3];
    const float* a2  = (const float*)d_in[4];
    const float* Wo  = (const float*)d_in[5];
    const float* ao1 = (const float*)d_in[6];
    const float* ao2 = (const float*)d_in[7];
    const float* W1  = (const float*)d_in[8];
    const float* b1  = (const float*)d_in[9];
    const float* W2  = (const float*)d_in[10];
    const float* b2  = (const float*)d_in[11];
    float* out = (float*)d_out;

    char* ws = (char*)d_ws;
    size_t off = 0;
    auto alloc = [&](size_t bytes) {
        void* p = ws + off;
        off += (bytes + 255) & ~(size_t)255;
        return p;
    };
    u64*     mbT    = (u64*)alloc((size_t)N_NODES * 64 * 8);
    u16*     xB     = (u16*)alloc((size_t)N_NODES * FIN * 2);
    u16*     WBt    = (u16*)alloc((size_t)NHEAD * DHEAD * FIN * 2);
    u16*     WoBt   = (u16*)alloc((size_t)DHEAD * FIN * 2);
    u16*     W1B    = (u16*)alloc((size_t)512 * N_NODES * 2);
    u16*     WhB    = (u16*)alloc((size_t)NHEAD * DHEAD * N_NODES * 2);
    u16*     WhoB   = (u16*)alloc((size_t)DHEAD * N_NODES * 2);
    u16*     hB     = (u16*)alloc((size_t)N_NODES * 512 * 2);
    float*   part8  = (float*)alloc((size_t)2 * N_NODES * 512 * 4);   // 16 MB
    float*   den8   = (float*)alloc((size_t)2 * 8 * N_NODES * 4);
    float*   f1b    = (float*)alloc((size_t)9 * N_NODES * 4);
    float*   f2b    = (float*)alloc((size_t)9 * N_NODES * 4);
    unsigned* gmk   = (unsigned*)alloc(16 * 4);
    float2*  rowc   = (float2*)alloc((size_t)9 * N_NODES * 8);
    float2*  uvb    = (float2*)alloc((size_t)9 * N_NODES * 8);
    // layer-2 scratch overlaid on part8 (dead after combine8)
    char*    ov     = (char*)part8;
    float*   partT1 = (float*)(ov);                                    // 8 MB
    float*   den1   = (float*)(ov + ((size_t)8 << 20));                // 128 KB
    u16*     lsT    = (u16*)(ov + ((size_t)8 << 20) + (256 << 10));    // 512 KB
    float*   part   = (float*)(ov + ((size_t)9 << 20));                // 2 MB
    (void)ws_size; (void)in_sizes; (void)n_in; (void)out_size;

    prep<<<5192, 256, 0, stream>>>(adj, mbT, gmk, x, xB, W1, W1B, W, Wo, WBt, WoBt);
    // layer 1
    gemm_fused<<<dim3(8, 64), 256, 0, stream>>>(xB, FIN, WBt, FIN, a1, a2,
                                                WhB, f1b, f2b, gmk, FIN);
    coefk<<<dim3(16, 8), 256, 0, stream>>>(f1b, f2b, gmk, rowc, uvb);
    attn_v5<8, 64, 2, 1><<<(N_NODES / 64) * 2 * 8, 256, 0, stream>>>(
        WhB, uvb, rowc, mbT, part8, den8);
    combine8<<<N_NODES * 512 / 4 / 256, 256, 0, stream>>>(part8, den8, hB);
    // layer 2
    gemm_fused<<<dim3(1, 64), 256, 0, stream>>>(hB, 512, WoBt, FIN, ao1, ao2,
                                                WhoB, f1b + (size_t)8 * N_NODES,
                                                f2b + (size_t)8 * N_NODES, gmk + 8, FIN);
    coefk<<<dim3(16, 1), 256, 0, stream>>>(f1b + (size_t)8 * N_NODES,
                                           f2b + (size_t)8 * N_NODES, gmk + 8,
                                           rowc + (size_t)8 * N_NODES,
                                           uvb + (size_t)8 * N_NODES);
    attn_v5<1, 64, 8, 3><<<(N_NODES / 64) * 8, 256, 0, stream>>>(
        WhoB, uvb + (size_t)8 * N_NODES, rowc + (size_t)8 * N_NODES, mbT, partT1, den1);
    combine1_lsm<<<64, 1024, 0, stream>>>(partT1, den1, lsT);
    // MLP head
    mlp1_mfma<<<128, 256, 0, stream>>>(lsT, W1B, part);
    mlp2f<<<64, 256, 0, stream>>>(part, b1, W2, b2, out);
}